// Round 4
// baseline (126.084 us; speedup 1.0000x reference)
//
#include <hip/hip_runtime.h>

#define HH 480
#define WW 640
#define NC 3
#define NVX 128           // W/SKIP
#define NVY 96            // H/SKIP
#define NV (NVX * NVY)    // 12288
#define NBX 80
#define NBY 60
#define NB (NBX * NBY)    // 4800
#define NBK 96                       // point buckets
#define BKT 128                      // bucket capacity
#define BINBLOCKS ((NB + 255) / 256) // 19
#define VOTEBLOCKS (BINBLOCKS * NBK) // 1824

// ---------------- kernel 1: gather + per-bucket stable compaction (vl>0 only) ----------------
// Bucket b (96 buckets, 128 slots): compacted vl>0 points of index range
// [b*128, b*128+128), ascending original order (deterministic ballot ranks).
// Also zeroes hough/dsum/done and emits per-bucket class histograms.
__global__ void precompute_pts(const int* __restrict__ label,
                               const float* __restrict__ vert,
                               float4* __restrict__ ptsA,
                               float4* __restrict__ ptsB,
                               int* __restrict__ cnt,
                               float* __restrict__ blockCounts,
                               float* __restrict__ hough,
                               float* __restrict__ dsum,
                               unsigned int* __restrict__ done) {
    __shared__ int swtot[2], sn2[2];
    const int tid = threadIdx.x;                 // 0..127
    const int i = blockIdx.x * BKT + tid;        // < NV (96*128 == 12288)
    const int iy = i >> 7;
    const int ix = i & (NVX - 1);
    const int pix = (5 * iy) * WW + 5 * ix;
    const int vl = label[pix];
    const float* base = vert + (size_t)(vl * 3) * HH * WW + pix;
    const float ux = base[0];
    const float uy = base[(size_t)HH * WW];
    const float dist = base[(size_t)2 * HH * WW];

    const bool pos = (vl > 0);
    const int lane = tid & 63, w = tid >> 6;
    unsigned long long mp = __ballot(pos);
    unsigned long long m2 = __ballot(vl == 2);
    int rank = __popcll(mp & ((1ull << lane) - 1ull));
    if (lane == 0) { swtot[w] = __popcll(mp); sn2[w] = __popcll(m2); }
    __syncthreads();
    if (pos) {
        int p = blockIdx.x * BKT + (w ? swtot[0] : 0) + rank;
        ptsA[p] = make_float4((float)(5 * ix), (float)(5 * iy), ux, uy);
        ptsB[p] = make_float4((vl == 1) ? dist : 0.0f,
                              (vl == 2) ? dist : 0.0f,
                              (vl == 1) ? 1.0f : 0.0f,
                              (vl == 2) ? 1.0f : 0.0f);
    }
    if (tid == 0) {
        int tot = swtot[0] + swtot[1];
        int n2 = sn2[0] + sn2[1];
        cnt[blockIdx.x] = tot;
        blockCounts[blockIdx.x * NC + 0] = (float)(BKT - tot);
        blockCounts[blockIdx.x * NC + 1] = (float)(tot - n2);
        blockCounts[blockIdx.x * NC + 2] = (float)n2;
    }
    // zero accumulation targets (NV threads total across grid)
    for (int k = i; k < NC * NB; k += NV) hough[k] = 0.0f;
    if (i < 2 * NB) dsum[i] = 0.0f;
    if (i == 0) *done = 0u;
}

// ---------------- kernel 2: voting + fused last-block finalize ----------------
// Squared test: cos>0.5 <=> dot>0 && dot^2 > 0.25*nx. Borderline pairs
// (|s| < nx*2e-5, ~30x the rounding band) recompute the reference's exact
// IEEE sequence -> decisions (hence hough/rois) bit-identical to np.
__global__ void vote(const float4* __restrict__ ptsA,
                     const float4* __restrict__ ptsB,
                     const int* __restrict__ cnt,
                     const float* __restrict__ blockCounts,
                     const float* __restrict__ meta,
                     const float* __restrict__ extents,
                     float* __restrict__ hough,
                     float* __restrict__ dsum,
                     float* __restrict__ rois,
                     unsigned int* __restrict__ done) {
    __shared__ float4 shA[BKT];
    __shared__ float4 shB[BKT];
    __shared__ unsigned long long skey[256];
    __shared__ float scnt[256];
    __shared__ int slast;

    const int tid = threadIdx.x;
    const int p0 = blockIdx.y * BKT;
    if (tid < BKT) shA[tid] = ptsA[p0 + tid];
    else           shB[tid - BKT] = ptsB[p0 + tid - BKT];
    const int n = cnt[blockIdx.y];

    const int b = blockIdx.x * 256 + tid;
    const float bxf = (float)(4 + 8 * (b % NBX));
    const float byf = (float)(4 + 8 * (b / NBX));
    float h1 = 0.f, h2 = 0.f, d1 = 0.f, d2 = 0.f;
    __syncthreads();

#pragma unroll 4
    for (int j = 0; j < n; ++j) {
        float4 a = shA[j];   // vx, vy, ux, uy
        float4 q = shB[j];   // z1, z2, c1, c2
        float ddx = bxf - a.x;
        float ddy = byf - a.y;
        float nx  = __builtin_fmaf(ddx, ddx, __builtin_fmaf(ddy, ddy, 1e-6f));
        float dot = __builtin_fmaf(ddx, a.z, ddy * a.w);
        float s   = __builtin_fmaf(dot, dot, -0.25f * nx);
        bool v = (dot > 0.0f) & (s > 0.0f);
        if (__builtin_expect((dot > 0.0f) && (fabsf(s) < nx * 2e-5f), 0)) {
            float nxe  = __fadd_rn(__fadd_rn(__fmul_rn(ddx, ddx),
                                             __fmul_rn(ddy, ddy)), 1e-6f);
            float inve = __fdiv_rn(1.0f, __fsqrt_rn(nxe));
            float dote = __fadd_rn(__fmul_rn(ddx, a.z), __fmul_rn(ddy, a.w));
            v = __fmul_rn(dote, inve) > 0.5f;
        }
        float m = v ? 1.0f : 0.0f;
        d1 = __builtin_fmaf(m, q.x, d1);
        d2 = __builtin_fmaf(m, q.y, d2);
        h1 = __builtin_fmaf(m, q.z, h1);
        h2 = __builtin_fmaf(m, q.w, h2);
    }
    if (b < NB) {
        atomicAdd(&hough[NB + b], h1);
        atomicAdd(&hough[2 * NB + b], h2);
        atomicAdd(&dsum[b], d1);
        atomicAdd(&dsum[NB + b], d2);
    }

    // ---- last-block finalize ----
    __syncthreads();
    if (tid == 0) {
        __threadfence();
        unsigned int old = atomicAdd(done, 1u);
        slast = (old == VOTEBLOCKS - 1u) ? 1 : 0;
    }
    __syncthreads();
    if (!slast) return;
    __threadfence();   // acquire: invalidate stale cached lines before reads

    for (int c = 0; c < NC; ++c) {
        float cv = 0.0f;
        if (tid < NBK) cv = blockCounts[tid * NC + c];
        // packed (value_bits, NB-1-i): max wins, ties -> smallest index
        unsigned long long best = 0ull;
        for (int i = tid; i < NB; i += 256) {
            float v = __hip_atomic_load(&hough[c * NB + i], __ATOMIC_RELAXED,
                                        __HIP_MEMORY_SCOPE_AGENT);
            unsigned long long key =
                ((unsigned long long)__float_as_uint(v) << 32) |
                (unsigned long long)(unsigned)(NB - 1 - i);
            if (key > best) best = key;
        }
        skey[tid] = best;
        scnt[tid] = cv;
        __syncthreads();
        for (int s = 128; s > 0; s >>= 1) {
            if (tid < s) {
                if (skey[tid + s] > skey[tid]) skey[tid] = skey[tid + s];
                scnt[tid] += scnt[tid + s];
            }
            __syncthreads();
        }
        if (tid == 0) {
            float votes = __uint_as_float((unsigned)(skey[0] >> 32));
            int peak = NB - 1 - (int)(skey[0] & 0xffffffffull);
            float ds = (c == 0) ? 0.0f
                     : __hip_atomic_load(&dsum[(c - 1) * NB + peak],
                                         __ATOMIC_RELAXED,
                                         __HIP_MEMORY_SCOPE_AGENT);
            float depth = __fdiv_rn(ds, fmaxf(votes, 1.0f));
            float cx = (float)(4 + 8 * (peak % NBX));
            float cy = (float)(4 + 8 * (peak / NBX));
            float cntf = scnt[0];
            float score = __fdiv_rn(votes, fmaxf(cntf, 1.0f));
            int valid = (cntf > 5.0f) && (score > 0.3f);
            float fx = meta[0], fy = meta[4];
            float e0 = extents[c * 3 + 0];
            float e1 = extents[c * 3 + 1];
            float e2 = extents[c * 3 + 2];
            float diag = __fsqrt_rn(__fadd_rn(
                __fadd_rn(__fmul_rn(e0, e0), __fmul_rn(e1, e1)),
                __fmul_rn(e2, e2)));
            float sz = fmaxf(fabsf(depth), 0.001f);
            float bw = __fdiv_rn(fabsf(__fmul_rn(diag, fx)), sz);
            float bh = __fdiv_rn(fabsf(__fmul_rn(diag, fy)), sz);
            rois[c * 6 + 0] = (float)c;
            rois[c * 6 + 1] = cx - bw * 0.5f;
            rois[c * 6 + 2] = cy - bh * 0.5f;
            rois[c * 6 + 3] = cx + bw * 0.5f;
            rois[c * 6 + 4] = cy + bh * 0.5f;
            rois[c * 6 + 5] = valid ? score : 0.0f;
        }
        __syncthreads();
    }
}

extern "C" void kernel_launch(void* const* d_in, const int* in_sizes, int n_in,
                              void* d_out, int out_size, void* d_ws, size_t ws_size,
                              hipStream_t stream) {
    const int* label = (const int*)d_in[0];
    const float* vert = (const float*)d_in[1];
    const float* meta = (const float*)d_in[2];
    const float* extents = (const float*)d_in[3];
    float* out = (float*)d_out;

    char* ws = (char*)d_ws;
    float4* ptsA = (float4*)ws;                                    // 196608 B
    float4* ptsB = (float4*)(ws + (size_t)NV * 16);                // 196608 B
    float* dsum = (float*)(ws + (size_t)2 * NV * 16);              // 38400 B
    float* blockCounts = (float*)(ws + (size_t)2 * NV * 16 + 2 * NB * 4);      // 1152 B
    int* cnt = (int*)(ws + (size_t)2 * NV * 16 + 2 * NB * 4 + NBK * NC * 4);   // 384 B
    unsigned int* done = (unsigned int*)(ws + (size_t)2 * NV * 16 + 2 * NB * 4
                                         + NBK * NC * 4 + NBK * 4);            // 4 B

    float* hough = out + NC * 6;  // 3*NB floats; rois occupy out[0..17]

    precompute_pts<<<NBK, BKT, 0, stream>>>(label, vert, ptsA, ptsB,
                                            cnt, blockCounts, hough, dsum, done);
    vote<<<dim3(BINBLOCKS, NBK), 256, 0, stream>>>(ptsA, ptsB, cnt, blockCounts,
                                                   meta, extents, hough, dsum,
                                                   out, done);
}

// Round 5
// 123.934 us; speedup vs baseline: 1.0174x; 1.0174x over previous
//
#include <hip/hip_runtime.h>

#define HH 480
#define WW 640
#define NC 3
#define NVX 128           // W/SKIP
#define NVY 96            // H/SKIP
#define NV (NVX * NVY)    // 12288
#define NBX 80
#define NBY 60
#define NB (NBX * NBY)    // 4800
#define NPB 48                       // point buckets (48*256 == NV)
#define XBLK 10                      // ceil((NB/2)/256) lane-blocks over bins

// ---------------- kernel 1: gather + per-bucket stable compaction (vl>0 only) ----------------
// Bucket b: compacted vl>0 points of [b*256, b*256+256), ascending original
// order (deterministic ballot ranks). Zeroes hough/dsum; per-bucket histograms.
__global__ void precompute_pts(const int* __restrict__ label,
                               const float* __restrict__ vert,
                               float4* __restrict__ ptsA,
                               float2* __restrict__ ptsB,
                               int* __restrict__ cnt,
                               float* __restrict__ blockCounts,
                               float* __restrict__ hough,
                               float* __restrict__ dsum) {
    __shared__ int swtot[4], sn2[4];
    const int tid = threadIdx.x;
    const int i = blockIdx.x * 256 + tid;        // < NV (48*256 == 12288)
    const int iy = i >> 7;
    const int ix = i & (NVX - 1);
    const int pix = (5 * iy) * WW + 5 * ix;
    const int vl = label[pix];
    const float* base = vert + (size_t)(vl * 3) * HH * WW + pix;
    const float ux = base[0];
    const float uy = base[(size_t)HH * WW];
    const float dist = base[(size_t)2 * HH * WW];

    const bool pos = (vl > 0);
    const int lane = tid & 63, w = tid >> 6;
    unsigned long long mp = __ballot(pos);
    unsigned long long m2 = __ballot(vl == 2);
    int rank = __popcll(mp & ((1ull << lane) - 1ull));
    if (lane == 0) { swtot[w] = __popcll(mp); sn2[w] = __popcll(m2); }
    __syncthreads();
    int off = 0;
    for (int k = 0; k < w; ++k) off += swtot[k];
    if (pos) {
        int p = blockIdx.x * 256 + off + rank;
        ptsA[p] = make_float4((float)(5 * ix), (float)(5 * iy), ux, uy);
        float2 pb; pb.x = dist; pb.y = __int_as_float(vl);
        ptsB[p] = pb;
    }
    if (tid == 0) {
        int tot = swtot[0] + swtot[1] + swtot[2] + swtot[3];
        int n2 = sn2[0] + sn2[1] + sn2[2] + sn2[3];
        cnt[blockIdx.x] = tot;
        blockCounts[blockIdx.x * NC + 0] = (float)(256 - tot);
        blockCounts[blockIdx.x * NC + 1] = (float)(tot - n2);
        blockCounts[blockIdx.x * NC + 2] = (float)n2;
    }
    for (int k = i; k < NC * NB; k += NV) hough[k] = 0.0f;
    if (i < 2 * NB) dsum[i] = 0.0f;
}

// ---------------- kernel 2: voting, 2 adjacent bins per lane ----------------
// Squared test: cos>0.5 <=> dot>0 && dot^2 > 0.25*nx. Borderline pairs
// (|s| < nx*2e-5) recompute the reference's exact IEEE sequence ->
// decisions (hence hough/rois) bit-identical to np.
// b0 even, b0%80 <= 78 -> bins b0,b0+1 share the row (byf, ddy terms shared).
__global__ void vote(const float4* __restrict__ ptsA,
                     const float2* __restrict__ ptsB,
                     const int* __restrict__ cnt,
                     float* __restrict__ hough,
                     float* __restrict__ dsum) {
    __shared__ float4 shA[256];
    __shared__ float2 shB[256];
    const int tid = threadIdx.x;
    const int p0 = blockIdx.y * 256;
    shA[tid] = ptsA[p0 + tid];
    shB[tid] = ptsB[p0 + tid];
    const int n = cnt[blockIdx.y];

    const int b0 = 2 * (blockIdx.x * 256 + tid);
    const float bx0 = (float)(4 + 8 * (b0 % NBX));
    const float bx1 = bx0 + 8.0f;
    const float byf = (float)(4 + 8 * (b0 / NBX));
    float h10 = 0.f, h20 = 0.f, d10 = 0.f, d20 = 0.f;
    float h11 = 0.f, h21 = 0.f, d11 = 0.f, d21 = 0.f;
    __syncthreads();

#pragma unroll 4
    for (int j = 0; j < n; ++j) {
        float4 a = shA[j];   // vx, vy, ux, uy
        float2 q = shB[j];   // z, cls-bits
        const int cls = __builtin_amdgcn_readfirstlane(__float_as_int(q.y));
        const float z = q.x;
        float ddy = byf - a.y;
        float dyt = __builtin_fmaf(ddy, ddy, 1e-6f);
        float dyu = ddy * a.w;

        float ddx0 = bx0 - a.x;
        float nx0  = __builtin_fmaf(ddx0, ddx0, dyt);
        float dot0 = __builtin_fmaf(ddx0, a.z, dyu);
        float s0   = __builtin_fmaf(dot0, dot0, -0.25f * nx0);
        bool v0 = (dot0 > 0.f) & (s0 > 0.f);

        float ddx1 = bx1 - a.x;
        float nx1  = __builtin_fmaf(ddx1, ddx1, dyt);
        float dot1 = __builtin_fmaf(ddx1, a.z, dyu);
        float s1   = __builtin_fmaf(dot1, dot1, -0.25f * nx1);
        bool v1 = (dot1 > 0.f) & (s1 > 0.f);

        if (__builtin_expect(((dot0 > 0.f) && (fabsf(s0) < nx0 * 2e-5f)) ||
                             ((dot1 > 0.f) && (fabsf(s1) < nx1 * 2e-5f)), 0)) {
            {   // exact reference sequence, bin 0
                float nxe  = __fadd_rn(__fadd_rn(__fmul_rn(ddx0, ddx0),
                                                 __fmul_rn(ddy, ddy)), 1e-6f);
                float inve = __fdiv_rn(1.0f, __fsqrt_rn(nxe));
                float dote = __fadd_rn(__fmul_rn(ddx0, a.z), __fmul_rn(ddy, a.w));
                v0 = __fmul_rn(dote, inve) > 0.5f;
            }
            {   // exact reference sequence, bin 1
                float nxe  = __fadd_rn(__fadd_rn(__fmul_rn(ddx1, ddx1),
                                                 __fmul_rn(ddy, ddy)), 1e-6f);
                float inve = __fdiv_rn(1.0f, __fsqrt_rn(nxe));
                float dote = __fadd_rn(__fmul_rn(ddx1, a.z), __fmul_rn(ddy, a.w));
                v1 = __fmul_rn(dote, inve) > 0.5f;
            }
        }
        float m0 = v0 ? 1.0f : 0.0f;
        float m1 = v1 ? 1.0f : 0.0f;
        if (cls == 1) {   // wave-uniform scalar branch (point class)
            h10 += m0; d10 = __builtin_fmaf(m0, z, d10);
            h11 += m1; d11 = __builtin_fmaf(m1, z, d11);
        } else {
            h20 += m0; d20 = __builtin_fmaf(m0, z, d20);
            h21 += m1; d21 = __builtin_fmaf(m1, z, d21);
        }
    }
    if (b0 < NB) {
        atomicAdd(&hough[NB + b0], h10);
        atomicAdd(&hough[2 * NB + b0], h20);
        atomicAdd(&dsum[b0], d10);
        atomicAdd(&dsum[NB + b0], d20);
        atomicAdd(&hough[NB + b0 + 1], h11);
        atomicAdd(&hough[2 * NB + b0 + 1], h21);
        atomicAdd(&dsum[b0 + 1], d11);
        atomicAdd(&dsum[NB + b0 + 1], d21);
    }
}

// ---------------- kernel 3: argmax + ROI math (one block per class) ----------------
__global__ void finalize(const float* __restrict__ hough,
                         const float* __restrict__ dsum,
                         const float* __restrict__ blockCounts,
                         const float* __restrict__ meta,
                         const float* __restrict__ extents,
                         float* __restrict__ rois) {
    __shared__ unsigned long long skey[256];
    __shared__ float scnt[256];
    const int tid = threadIdx.x;
    const int c = blockIdx.x;

    float cntv = 0.0f;
    for (int i = tid; i < NPB; i += 256) cntv += blockCounts[i * NC + c];
    scnt[tid] = cntv;

    unsigned long long best = 0ull;
    for (int i = tid; i < NB; i += 256) {
        float v = hough[c * NB + i];
        unsigned long long key =
            ((unsigned long long)__float_as_uint(v) << 32) |
            (unsigned long long)(unsigned)(NB - 1 - i);
        if (key > best) best = key;
    }
    skey[tid] = best;
    __syncthreads();
    for (int s = 128; s > 0; s >>= 1) {
        if (tid < s) {
            if (skey[tid + s] > skey[tid]) skey[tid] = skey[tid + s];
            scnt[tid] += scnt[tid + s];
        }
        __syncthreads();
    }
    if (tid == 0) {
        float votes = __uint_as_float((unsigned)(skey[0] >> 32));
        int peak = NB - 1 - (int)(skey[0] & 0xffffffffull);
        float ds = (c == 0) ? 0.0f : dsum[(c - 1) * NB + peak];
        float depth = __fdiv_rn(ds, fmaxf(votes, 1.0f));
        float cx = (float)(4 + 8 * (peak % NBX));
        float cy = (float)(4 + 8 * (peak / NBX));
        float cntf = scnt[0];
        float score = __fdiv_rn(votes, fmaxf(cntf, 1.0f));
        int valid = (cntf > 5.0f) && (score > 0.3f);
        float fx = meta[0], fy = meta[4];
        float e0 = extents[c * 3 + 0];
        float e1 = extents[c * 3 + 1];
        float e2 = extents[c * 3 + 2];
        float diag = __fsqrt_rn(__fadd_rn(
            __fadd_rn(__fmul_rn(e0, e0), __fmul_rn(e1, e1)), __fmul_rn(e2, e2)));
        float sz = fmaxf(fabsf(depth), 0.001f);
        float bw = __fdiv_rn(fabsf(__fmul_rn(diag, fx)), sz);
        float bh = __fdiv_rn(fabsf(__fmul_rn(diag, fy)), sz);
        rois[c * 6 + 0] = (float)c;
        rois[c * 6 + 1] = cx - bw * 0.5f;
        rois[c * 6 + 2] = cy - bh * 0.5f;
        rois[c * 6 + 3] = cx + bw * 0.5f;
        rois[c * 6 + 4] = cy + bh * 0.5f;
        rois[c * 6 + 5] = valid ? score : 0.0f;
    }
}

extern "C" void kernel_launch(void* const* d_in, const int* in_sizes, int n_in,
                              void* d_out, int out_size, void* d_ws, size_t ws_size,
                              hipStream_t stream) {
    const int* label = (const int*)d_in[0];
    const float* vert = (const float*)d_in[1];
    const float* meta = (const float*)d_in[2];
    const float* extents = (const float*)d_in[3];
    float* out = (float*)d_out;

    char* ws = (char*)d_ws;
    float4* ptsA = (float4*)ws;                                    // 196608 B
    float2* ptsB = (float2*)(ws + (size_t)NV * 16);                // 98304 B
    float* dsum = (float*)(ws + (size_t)NV * 24);                  // 38400 B
    float* blockCounts = (float*)(ws + (size_t)NV * 24 + 2 * NB * 4);          // 576 B
    int* cnt = (int*)(ws + (size_t)NV * 24 + 2 * NB * 4 + NPB * NC * 4);       // 192 B

    float* hough = out + NC * 6;  // 3*NB floats; rois occupy out[0..17]

    precompute_pts<<<NPB, 256, 0, stream>>>(label, vert, ptsA, ptsB,
                                            cnt, blockCounts, hough, dsum);
    vote<<<dim3(XBLK, NPB), 256, 0, stream>>>(ptsA, ptsB, cnt, hough, dsum);
    finalize<<<NC, 256, 0, stream>>>(hough, dsum, blockCounts, meta, extents, out);
}

// Round 6
// 112.957 us; speedup vs baseline: 1.1162x; 1.0972x over previous
//
#include <hip/hip_runtime.h>

#define HH 480
#define WW 640
#define NC 3
#define NVX 128           // W/SKIP
#define NVY 96            // H/SKIP
#define NV (NVX * NVY)    // 12288
#define NBX 80
#define NBY 60
#define NB (NBX * NBY)    // 4800
#define NPB 96                       // point buckets (96*128 == NV)
#define BKT 128                      // bucket capacity
#define XBLK 10                      // ceil((NB/2)/256) lane-blocks over bins

// ---------------- kernel 1: gather + per-bucket stable compaction (vl>0 only) ----------------
__global__ void precompute_pts(const int* __restrict__ label,
                               const float* __restrict__ vert,
                               float4* __restrict__ ptsA,
                               float4* __restrict__ ptsB,
                               int* __restrict__ cnt,
                               float* __restrict__ blockCounts,
                               float* __restrict__ hough,
                               float* __restrict__ dsum) {
    __shared__ int swtot[2], sn2[2];
    const int tid = threadIdx.x;                 // 0..127
    const int i = blockIdx.x * BKT + tid;        // < NV (96*128 == 12288)
    const int iy = i >> 7;
    const int ix = i & (NVX - 1);
    const int pix = (5 * iy) * WW + 5 * ix;
    const int vl = label[pix];
    const float* base = vert + (size_t)(vl * 3) * HH * WW + pix;
    const float ux = base[0];
    const float uy = base[(size_t)HH * WW];
    const float dist = base[(size_t)2 * HH * WW];

    const bool pos = (vl > 0);
    const int lane = tid & 63, w = tid >> 6;
    unsigned long long mp = __ballot(pos);
    unsigned long long m2 = __ballot(vl == 2);
    int rank = __popcll(mp & ((1ull << lane) - 1ull));
    if (lane == 0) { swtot[w] = __popcll(mp); sn2[w] = __popcll(m2); }
    __syncthreads();
    if (pos) {
        int p = blockIdx.x * BKT + (w ? swtot[0] : 0) + rank;
        ptsA[p] = make_float4((float)(5 * ix), (float)(5 * iy), ux, uy);
        ptsB[p] = make_float4((vl == 1) ? dist : 0.0f,
                              (vl == 2) ? dist : 0.0f,
                              (vl == 1) ? 1.0f : 0.0f,
                              (vl == 2) ? 1.0f : 0.0f);
    }
    if (tid == 0) {
        int tot = swtot[0] + swtot[1];
        int n2 = sn2[0] + sn2[1];
        cnt[blockIdx.x] = tot;
        blockCounts[blockIdx.x * NC + 0] = (float)(BKT - tot);
        blockCounts[blockIdx.x * NC + 1] = (float)(tot - n2);
        blockCounts[blockIdx.x * NC + 2] = (float)n2;
    }
    // zero accumulation targets (NV threads total across grid)
    for (int k = i; k < NC * NB; k += NV) hough[k] = 0.0f;
    if (i < 2 * NB) dsum[i] = 0.0f;
}

// ---------------- kernel 2: voting, 2 adjacent bins/lane, branchless inner loop ----------------
// Fast test: cos>0.5 <=> dot>0 && s>0, s = dot^2 - 0.25*nx (0.25*nx exact).
// Flag band |s| < nx*1e-6 (>=5x the combined rounding zone ~2e-7): flagged
// lanes re-run the bucket post-loop applying (m_exact - m_fast) deltas with
// the reference's exact IEEE sequence -> hough counts (exact small ints) and
// all decisions bit-identical to the np reference.
__global__ void vote(const float4* __restrict__ ptsA,
                     const float4* __restrict__ ptsB,
                     const int* __restrict__ cnt,
                     float* __restrict__ hough,
                     float* __restrict__ dsum) {
    __shared__ float4 shA[BKT];
    __shared__ float4 shB[BKT];
    const int tid = threadIdx.x;
    const int p0 = blockIdx.y * BKT;
    if (tid < BKT) shA[tid] = ptsA[p0 + tid];
    else           shB[tid - BKT] = ptsB[p0 + tid - BKT];
    const int n = cnt[blockIdx.y];

    const int b0 = 2 * (blockIdx.x * 256 + tid);
    const float bx0 = (float)(4 + 8 * (b0 % NBX));
    const float bx1 = bx0 + 8.0f;
    const float byf = (float)(4 + 8 * (b0 / NBX));
    float h10 = 0.f, h20 = 0.f, d10 = 0.f, d20 = 0.f;
    float h11 = 0.f, h21 = 0.f, d11 = 0.f, d21 = 0.f;
    float flagacc = -1.0f;
    __syncthreads();

    for (int j = 0; j < n; ++j) {
        float4 a = shA[j];   // vx, vy, ux, uy
        float4 q = shB[j];   // z1, z2, c1, c2
        float ddy = byf - a.y;
        float dyt = __builtin_fmaf(ddy, ddy, 1e-6f);
        float dyu = ddy * a.w;

        float ddx0 = bx0 - a.x;
        float nx0  = __builtin_fmaf(ddx0, ddx0, dyt);
        float dot0 = __builtin_fmaf(ddx0, a.z, dyu);
        float s0   = __builtin_fmaf(dot0, dot0, -0.25f * nx0);
        float g0   = fminf(dot0, s0);                              // >0 iff vote
        float f0   = fminf(dot0, __builtin_fmaf(nx0, 1e-6f, -fabsf(s0)));

        float ddx1 = bx1 - a.x;
        float nx1  = __builtin_fmaf(ddx1, ddx1, dyt);
        float dot1 = __builtin_fmaf(ddx1, a.z, dyu);
        float s1   = __builtin_fmaf(dot1, dot1, -0.25f * nx1);
        float g1   = fminf(dot1, s1);
        float f1   = fminf(dot1, __builtin_fmaf(nx1, 1e-6f, -fabsf(s1)));

        flagacc = fmaxf(flagacc, fmaxf(f0, f1));
        float m0 = (g0 > 0.0f) ? 1.0f : 0.0f;
        float m1 = (g1 > 0.0f) ? 1.0f : 0.0f;
        d10 = __builtin_fmaf(m0, q.x, d10);
        d20 = __builtin_fmaf(m0, q.y, d20);
        h10 = __builtin_fmaf(m0, q.z, h10);
        h20 = __builtin_fmaf(m0, q.w, h20);
        d11 = __builtin_fmaf(m1, q.x, d11);
        d21 = __builtin_fmaf(m1, q.y, d21);
        h11 = __builtin_fmaf(m1, q.z, h11);
        h21 = __builtin_fmaf(m1, q.w, h21);
    }

    // ---- rare correction pass (flagged lanes only; ~2% of waves enter) ----
    if (b0 >= NB) flagacc = -1.0f;
    if (flagacc > 0.0f) {
        for (int j = 0; j < n; ++j) {
            float4 a = shA[j];
            float4 q = shB[j];
            float ddy = byf - a.y;
            float dyt = __builtin_fmaf(ddy, ddy, 1e-6f);
            float dyu = ddy * a.w;
#pragma unroll
            for (int k = 0; k < 2; ++k) {
                float bx = k ? bx1 : bx0;
                float ddx = bx - a.x;
                float nx  = __builtin_fmaf(ddx, ddx, dyt);
                float dot = __builtin_fmaf(ddx, a.z, dyu);
                float s   = __builtin_fmaf(dot, dot, -0.25f * nx);
                float mf  = (fminf(dot, s) > 0.0f) ? 1.0f : 0.0f;
                // exact reference op sequence
                float nxe  = __fadd_rn(__fadd_rn(__fmul_rn(ddx, ddx),
                                                 __fmul_rn(ddy, ddy)), 1e-6f);
                float inve = __fdiv_rn(1.0f, __fsqrt_rn(nxe));
                float dote = __fadd_rn(__fmul_rn(ddx, a.z), __fmul_rn(ddy, a.w));
                float me   = (__fmul_rn(dote, inve) > 0.5f) ? 1.0f : 0.0f;
                float dm   = me - mf;   // in {-1,0,1}, exact
                if (k == 0) {
                    d10 = __builtin_fmaf(dm, q.x, d10);
                    d20 = __builtin_fmaf(dm, q.y, d20);
                    h10 = __builtin_fmaf(dm, q.z, h10);
                    h20 = __builtin_fmaf(dm, q.w, h20);
                } else {
                    d11 = __builtin_fmaf(dm, q.x, d11);
                    d21 = __builtin_fmaf(dm, q.y, d21);
                    h11 = __builtin_fmaf(dm, q.z, h11);
                    h21 = __builtin_fmaf(dm, q.w, h21);
                }
            }
        }
    }

    if (b0 < NB) {
        atomicAdd(&hough[NB + b0], h10);
        atomicAdd(&hough[2 * NB + b0], h20);
        atomicAdd(&dsum[b0], d10);
        atomicAdd(&dsum[NB + b0], d20);
        atomicAdd(&hough[NB + b0 + 1], h11);
        atomicAdd(&hough[2 * NB + b0 + 1], h21);
        atomicAdd(&dsum[b0 + 1], d11);
        atomicAdd(&dsum[NB + b0 + 1], d21);
    }
}

// ---------------- kernel 3: argmax + ROI math (one block per class) ----------------
__global__ void finalize(const float* __restrict__ hough,
                         const float* __restrict__ dsum,
                         const float* __restrict__ blockCounts,
                         const float* __restrict__ meta,
                         const float* __restrict__ extents,
                         float* __restrict__ rois) {
    __shared__ unsigned long long skey[256];
    __shared__ float scnt[256];
    const int tid = threadIdx.x;
    const int c = blockIdx.x;

    float cntv = 0.0f;
    for (int i = tid; i < NPB; i += 256) cntv += blockCounts[i * NC + c];
    scnt[tid] = cntv;

    unsigned long long best = 0ull;
    for (int i = tid; i < NB; i += 256) {
        float v = hough[c * NB + i];
        unsigned long long key =
            ((unsigned long long)__float_as_uint(v) << 32) |
            (unsigned long long)(unsigned)(NB - 1 - i);
        if (key > best) best = key;
    }
    skey[tid] = best;
    __syncthreads();
    for (int s = 128; s > 0; s >>= 1) {
        if (tid < s) {
            if (skey[tid + s] > skey[tid]) skey[tid] = skey[tid + s];
            scnt[tid] += scnt[tid + s];
        }
        __syncthreads();
    }
    if (tid == 0) {
        float votes = __uint_as_float((unsigned)(skey[0] >> 32));
        int peak = NB - 1 - (int)(skey[0] & 0xffffffffull);
        float ds = (c == 0) ? 0.0f : dsum[(c - 1) * NB + peak];
        float depth = __fdiv_rn(ds, fmaxf(votes, 1.0f));
        float cx = (float)(4 + 8 * (peak % NBX));
        float cy = (float)(4 + 8 * (peak / NBX));
        float cntf = scnt[0];
        float score = __fdiv_rn(votes, fmaxf(cntf, 1.0f));
        int valid = (cntf > 5.0f) && (score > 0.3f);
        float fx = meta[0], fy = meta[4];
        float e0 = extents[c * 3 + 0];
        float e1 = extents[c * 3 + 1];
        float e2 = extents[c * 3 + 2];
        float diag = __fsqrt_rn(__fadd_rn(
            __fadd_rn(__fmul_rn(e0, e0), __fmul_rn(e1, e1)), __fmul_rn(e2, e2)));
        float sz = fmaxf(fabsf(depth), 0.001f);
        float bw = __fdiv_rn(fabsf(__fmul_rn(diag, fx)), sz);
        float bh = __fdiv_rn(fabsf(__fmul_rn(diag, fy)), sz);
        rois[c * 6 + 0] = (float)c;
        rois[c * 6 + 1] = cx - bw * 0.5f;
        rois[c * 6 + 2] = cy - bh * 0.5f;
        rois[c * 6 + 3] = cx + bw * 0.5f;
        rois[c * 6 + 4] = cy + bh * 0.5f;
        rois[c * 6 + 5] = valid ? score : 0.0f;
    }
}

extern "C" void kernel_launch(void* const* d_in, const int* in_sizes, int n_in,
                              void* d_out, int out_size, void* d_ws, size_t ws_size,
                              hipStream_t stream) {
    const int* label = (const int*)d_in[0];
    const float* vert = (const float*)d_in[1];
    const float* meta = (const float*)d_in[2];
    const float* extents = (const float*)d_in[3];
    float* out = (float*)d_out;

    char* ws = (char*)d_ws;
    float4* ptsA = (float4*)ws;                                    // 196608 B
    float4* ptsB = (float4*)(ws + (size_t)NV * 16);                // 196608 B
    float* dsum = (float*)(ws + (size_t)2 * NV * 16);              // 38400 B
    float* blockCounts = (float*)(ws + (size_t)2 * NV * 16 + 2 * NB * 4);      // 1152 B
    int* cnt = (int*)(ws + (size_t)2 * NV * 16 + 2 * NB * 4 + NPB * NC * 4);   // 384 B

    float* hough = out + NC * 6;  // 3*NB floats; rois occupy out[0..17]

    precompute_pts<<<NPB, BKT, 0, stream>>>(label, vert, ptsA, ptsB,
                                            cnt, blockCounts, hough, dsum);
    vote<<<dim3(XBLK, NPB), 256, 0, stream>>>(ptsA, ptsB, cnt, hough, dsum);
    finalize<<<NC, 256, 0, stream>>>(hough, dsum, blockCounts, meta, extents, out);
}